// Round 21
// baseline (123.318 us; speedup 1.0000x reference)
//
#include <hip/hip_runtime.h>

#define IND 256
#define KC  32

__global__ __launch_bounds__(512, 8)
void FeatureEncodingLayer_30374008718005_kernel(
        const float* __restrict__ X,      // [1024][256]
        const float* __restrict__ W,      // [4096][256]
        const float* __restrict__ bias,   // [4096]
        float* __restrict__ outf)         // [1024][4][4][2048] float32 = Re(kron)
{
    // Pair-interleaved, XOR-swizzled W tile (verified R17/R20):
    // word (kp, u, k&1) at Ws[buf][kp][(2u+(k&1)) ^ ((kp&7)<<2)], kp = k>>1.
    __shared__ float Ws[2][KC / 2][256];   // 32 KB -> 4 blocks/CU, 32 waves/CU

    const int tid  = threadIdx.x;
    const int lane = tid & 63;
    const int wid  = __builtin_amdgcn_readfirstlane(tid >> 6);  // wave 0..7

    const int ut = blockIdx.x & 31;    // 32 unit tiles x 128 units
    const int bt = blockIdx.x >> 5;    // 16 batch tiles x 64 batches
    const int b0 = bt * 64 + 8 * wid;  // wave's 8 batches (wave-uniform)
    const int u0 = ut * 128;
    const int p0 = ut * 64;

    const int q  = tid & 7;            // k-quad: local k = 4q..4q+3
    const int rq = tid >> 3;           // row subgroup 0..63

    const float* xc = X + (size_t)b0 * IND;   // wave-uniform -> s_load

    float acc[8][2];
#pragma unroll
    for (int i = 0; i < 8; ++i) { acc[i][0] = 0.f; acc[i][1] = 0.f; }

    float4 pf[2];
#define STAGE_LOAD(c) do {                                                     \
    _Pragma("unroll")                                                          \
    for (int j = 0; j < 2; ++j)                                                \
        pf[j] = *reinterpret_cast<const float4*>(                              \
            W + (size_t)(u0 + rq + 64 * j) * IND + (c) * KC + q * 4);          \
    } while (0)

#define STAGE_WRITE(buf) do {                                                  \
    const int kp0 = 2 * q, kp1 = 2 * q + 1;                                    \
    const int sw0 = (kp0 & 7) << 2, sw1 = (kp1 & 7) << 2;                      \
    _Pragma("unroll")                                                          \
    for (int j = 0; j < 2; ++j) {                                              \
        const int u2 = 2 * (rq + 64 * j);                                      \
        *reinterpret_cast<float2*>(&Ws[buf][kp0][u2 ^ sw0]) =                  \
            make_float2(pf[j].x, pf[j].y);                                     \
        *reinterpret_cast<float2*>(&Ws[buf][kp1][u2 ^ sw1]) =                  \
            make_float2(pf[j].z, pf[j].w);                                     \
    }                                                                          \
    } while (0)

    // LDS-only barrier: global stores stay in flight (no vmcnt(0) drain).
#define LDS_BARRIER() do {                                                     \
    asm volatile("s_waitcnt lgkmcnt(0)" ::: "memory");                         \
    __builtin_amdgcn_s_barrier();                                              \
    } while (0)

    STAGE_LOAD(0);
    STAGE_WRITE(0);
    LDS_BARRIER();

    for (int c = 0; c < IND / KC; ++c) {
        const int cur = c & 1;
        if (c < IND / KC - 1) STAGE_LOAD(c + 1);   // prefetch (no wait yet)

        // zero-slot stores (half the output), one rc per chunk, issued after
        // the prefetch loads; never drained by the LDS-only barriers.
        {
            const int zrc = (int)((0xEDB87421u >> (4 * c)) & 0xFu);
            float* zp = outf + (size_t)b0 * 32768 + (size_t)zrc * 2048 + p0 + lane;
#pragma unroll
            for (int i = 0; i < 8; ++i)
                zp[(size_t)i * 32768] = 0.f;       // coalesced 256B per wave
        }

        // compute: per kp, 1 conflict-free ds_read_b128 + 32 FMA
#pragma unroll
        for (int kp = 0; kp < KC / 2; ++kp) {
            const int sw = (kp & 7) << 2;
            const float4 wq = *reinterpret_cast<const float4*>(
                &Ws[cur][kp][(4 * lane) ^ sw]);
            const int kg = c * KC + 2 * kp;
#pragma unroll
            for (int i = 0; i < 8; ++i) {
                const float x0 = xc[i * IND + kg];      // wave-uniform s_load
                const float x1 = xc[i * IND + kg + 1];
                acc[i][0] = fmaf(x0, wq.x, acc[i][0]);
                acc[i][0] = fmaf(x1, wq.y, acc[i][0]);
                acc[i][1] = fmaf(x0, wq.z, acc[i][1]);
                acc[i][1] = fmaf(x1, wq.w, acc[i][1]);
            }
        }
        if (c < IND / KC - 1) {
            STAGE_WRITE(cur ^ 1);                  // vmcnt wait: only its loads
            LDS_BARRIER();
        }
    }
#undef STAGE_LOAD
#undef STAGE_WRITE
#undef LDS_BARRIER

    // ---- epilogue: lane owns pair p0+lane (units u0+2lane, +1), 8 batches ----
    const float2 bv = *reinterpret_cast<const float2*>(bias + u0 + 2 * lane);

#pragma unroll
    for (int i = 0; i < 8; ++i) {
        const int b = b0 + i;
        const float tA = acc[i][0] + bv.x;
        const float tB = acc[i][1] + bv.y;
        float sA, cA, sB, cB;
        __sincosf(tA, &sA, &cA);
        __sincosf(tB, &sB, &cB);
        const float ca = 0.5f * (1.f + cA);   // cos^2(tA/2)
        const float sa = 0.5f * (1.f - cA);   // sin^2(tA/2)
        const float cb = 0.5f * (1.f + cB);
        const float sb = 0.5f * (1.f - cB);
        const float oo = 0.25f * sA * sB;     // sin(tA)/2 * sin(tB)/2

        float* bp = outf + (size_t)b * 32768 + p0 + lane;
        bp[ 0 * 2048] =  ca * cb;
        bp[ 3 * 2048] = -oo;
        bp[ 5 * 2048] =  ca * sb;
        bp[ 6 * 2048] =  oo;
        bp[ 9 * 2048] =  oo;
        bp[10 * 2048] =  sa * cb;
        bp[12 * 2048] = -oo;
        bp[15 * 2048] =  sa * sb;
    }
}

extern "C" void kernel_launch(void* const* d_in, const int* in_sizes, int n_in,
                              void* d_out, int out_size, void* d_ws, size_t ws_size,
                              hipStream_t stream) {
    const float* X  = (const float*)d_in[0];
    const float* W  = (const float*)d_in[1];
    const float* bv = (const float*)d_in[2];

    // 16 bt x 32 ut = 512 blocks x 512 threads; 32KB LDS -> 4 blocks/CU
    // = 32 waves/CU (8/SIMD): 2x the latency-hiding of R20 at same per-wave work.
    FeatureEncodingLayer_30374008718005_kernel<<<dim3(512), dim3(512), 0, stream>>>(
        X, W, bv, (float*)d_out);
}

// Round 22
// 79.175 us; speedup vs baseline: 1.5575x; 1.5575x over previous
//
#include <hip/hip_runtime.h>

#define IND 256
#define KC  32

__global__ __launch_bounds__(256, 4)
void FeatureEncodingLayer_30374008718005_kernel(
        const float* __restrict__ X,      // [1024][256]
        const float* __restrict__ W,      // [4096][256]
        const float* __restrict__ bias,   // [4096]
        float* __restrict__ outf)         // [1024][4][4][2048] float32 = Re(kron)
{
    // Pair-interleaved, XOR-swizzled W tile (verified R17/R20):
    // word (kp, u, k&1) at Ws[buf][kp][(2u+(k&1)) ^ ((kp&7)<<2)], kp = k>>1.
    __shared__ float Ws[2][KC / 2][256];   // 32 KB

    const int tid  = threadIdx.x;
    const int lane = tid & 63;
    const int wid  = __builtin_amdgcn_readfirstlane(tid >> 6);  // wave 0..3

    const int ut = blockIdx.x & 31;    // 32 unit tiles x 128 units
    const int bt = blockIdx.x >> 5;    // 32 batch tiles x 32 batches
    const int b0 = bt * 32;
    const int u0 = ut * 128;
    const int p0 = ut * 64;

    const int q  = tid & 7;            // k-quad: local k = 4q..4q+3
    const int rq = tid >> 3;           // row subgroup 0..31

    // X pointer made DIVERGENT (mbcnt is divergent to LLVM; value is 0):
    // forces global_load (VMEM/vmcnt) instead of s_load (SMEM/lgkmcnt), so
    // lgkmcnt tracks DS only -> precise counted waits -> pipelined ds_reads.
    // (SMEM retires out-of-order; mixed SMEM+DS forces lgkmcnt(0) per wait.)
    const int dz = (int)__builtin_amdgcn_mbcnt_lo(0u, 0u);
    const float* xv = X + (size_t)(b0 + 8 * wid) * IND + dz;

    float acc[8][2];
#pragma unroll
    for (int i = 0; i < 8; ++i) { acc[i][0] = 0.f; acc[i][1] = 0.f; }

    float4 pf[4];
#define STAGE_LOAD(c) do {                                                     \
    _Pragma("unroll")                                                          \
    for (int j = 0; j < 4; ++j)                                                \
        pf[j] = *reinterpret_cast<const float4*>(                              \
            W + (size_t)(u0 + rq + 32 * j) * IND + (c) * KC + q * 4);          \
    } while (0)

#define STAGE_WRITE(buf) do {                                                  \
    const int kp0 = 2 * q, kp1 = 2 * q + 1;                                    \
    const int sw0 = (kp0 & 7) << 2, sw1 = (kp1 & 7) << 2;                      \
    _Pragma("unroll")                                                          \
    for (int j = 0; j < 4; ++j) {                                              \
        const int u2 = 2 * (rq + 32 * j);                                      \
        *reinterpret_cast<float2*>(&Ws[buf][kp0][u2 ^ sw0]) =                  \
            make_float2(pf[j].x, pf[j].y);                                     \
        *reinterpret_cast<float2*>(&Ws[buf][kp1][u2 ^ sw1]) =                  \
            make_float2(pf[j].z, pf[j].w);                                     \
    }                                                                          \
    } while (0)

    // LDS-only barrier: global loads/stores stay in flight across it.
#define LDS_BARRIER() do {                                                     \
    asm volatile("s_waitcnt lgkmcnt(0)" ::: "memory");                         \
    __builtin_amdgcn_s_barrier();                                              \
    } while (0)

    STAGE_LOAD(0);
    STAGE_WRITE(0);
    LDS_BARRIER();

    for (int c = 0; c < IND / KC; ++c) {
        const int cur = c & 1;
        if (c < IND / KC - 1) STAGE_LOAD(c + 1);   // prefetch (no wait yet)

        // ---- compute: per t, 8 broadcast X float4 loads (VMEM) +
        //      2 conflict-free ds_read_b128 (W) + 64 FMA ----
#pragma unroll
        for (int t = 0; t < 8; ++t) {
            float4 xq[8];
#pragma unroll
            for (int i = 0; i < 8; ++i)
                xq[i] = *reinterpret_cast<const float4*>(
                    xv + i * IND + c * KC + 4 * t);

            const int kp0 = 2 * t, kp1 = 2 * t + 1;
            const int sw0 = (kp0 & 7) << 2, sw1 = (kp1 & 7) << 2;
            const float4 w0 = *reinterpret_cast<const float4*>(
                &Ws[cur][kp0][(4 * lane) ^ sw0]);
            const float4 w1 = *reinterpret_cast<const float4*>(
                &Ws[cur][kp1][(4 * lane) ^ sw1]);
            // w0 = {W[2l][4t],  W[2l][4t+1], W[2l+1][4t],  W[2l+1][4t+1]}
            // w1 = {W[2l][4t+2],W[2l][4t+3], W[2l+1][4t+2],W[2l+1][4t+3]}
#pragma unroll
            for (int i = 0; i < 8; ++i) {
                acc[i][0] = fmaf(xq[i].x, w0.x, acc[i][0]);
                acc[i][0] = fmaf(xq[i].y, w0.y, acc[i][0]);
                acc[i][0] = fmaf(xq[i].z, w1.x, acc[i][0]);
                acc[i][0] = fmaf(xq[i].w, w1.y, acc[i][0]);
                acc[i][1] = fmaf(xq[i].x, w0.z, acc[i][1]);
                acc[i][1] = fmaf(xq[i].y, w0.w, acc[i][1]);
                acc[i][1] = fmaf(xq[i].z, w1.z, acc[i][1]);
                acc[i][1] = fmaf(xq[i].w, w1.w, acc[i][1]);
            }
        }
        if (c < IND / KC - 1) {
            STAGE_WRITE(cur ^ 1);                  // vmcnt wait: only its loads
            LDS_BARRIER();
        }
    }
#undef STAGE_LOAD
#undef STAGE_WRITE
#undef LDS_BARRIER

    // ---- epilogue: lane owns pair p0+lane (units u0+2lane, +1), 8 batches;
    // all 16 slots stored here (zeros back in epilogue: they must not share
    // vmcnt with the in-loop X loads).
    const float2 bv = *reinterpret_cast<const float2*>(bias + u0 + 2 * lane);

#pragma unroll
    for (int i = 0; i < 8; ++i) {
        const int b = b0 + 8 * wid + i;
        const float tA = acc[i][0] + bv.x;
        const float tB = acc[i][1] + bv.y;
        float sA, cA, sB, cB;
        __sincosf(tA, &sA, &cA);
        __sincosf(tB, &sB, &cB);
        const float ca = 0.5f * (1.f + cA);   // cos^2(tA/2)
        const float sa = 0.5f * (1.f - cA);   // sin^2(tA/2)
        const float cb = 0.5f * (1.f + cB);
        const float sb = 0.5f * (1.f - cB);
        const float oo = 0.25f * sA * sB;     // sin(tA)/2 * sin(tB)/2

        float* bp = outf + (size_t)b * 32768 + p0 + lane;
        bp[ 0 * 2048] =  ca * cb;
        bp[ 1 * 2048] = 0.f;
        bp[ 2 * 2048] = 0.f;
        bp[ 3 * 2048] = -oo;
        bp[ 4 * 2048] = 0.f;
        bp[ 5 * 2048] =  ca * sb;
        bp[ 6 * 2048] =  oo;
        bp[ 7 * 2048] = 0.f;
        bp[ 8 * 2048] = 0.f;
        bp[ 9 * 2048] =  oo;
        bp[10 * 2048] =  sa * cb;
        bp[11 * 2048] = 0.f;
        bp[12 * 2048] = -oo;
        bp[13 * 2048] = 0.f;
        bp[14 * 2048] = 0.f;
        bp[15 * 2048] =  sa * sb;
    }
}

extern "C" void kernel_launch(void* const* d_in, const int* in_sizes, int n_in,
                              void* d_out, int out_size, void* d_ws, size_t ws_size,
                              hipStream_t stream) {
    const float* X  = (const float*)d_in[0];
    const float* W  = (const float*)d_in[1];
    const float* bv = (const float*)d_in[2];

    // R20's proven shape: 32 bt x 32 ut = 1024 blocks, 256 threads, 4 blocks/CU.
    FeatureEncodingLayer_30374008718005_kernel<<<dim3(1024), dim3(256), 0, stream>>>(
        X, W, bv, (float*)d_out);
}

// Round 23
// 44.250 us; speedup vs baseline: 2.7869x; 1.7893x over previous
//
#include <hip/hip_runtime.h>

#define IND 256
#define KC  32

__global__ __launch_bounds__(256, 4)
void FeatureEncodingLayer_30374008718005_kernel(
        const float* __restrict__ X,      // [1024][256]
        const float* __restrict__ W,      // [4096][256]
        const float* __restrict__ bias,   // [4096]
        float* __restrict__ outf)         // [1024][4][4][2048] float32 = Re(kron)
{
    // Pair-interleaved, XOR-swizzled W tile (verified R17/R20):
    // word (kp, u, k&1) at Ws[buf][kp][(2u+(k&1)) ^ ((kp&7)<<2)], kp = k>>1.
    __shared__ float Ws[2][KC / 2][256];   // 32 KB

    const int tid  = threadIdx.x;
    const int lane = tid & 63;
    const int wid  = __builtin_amdgcn_readfirstlane(tid >> 6);  // wave 0..3

    const int ut = blockIdx.x & 31;    // 32 unit tiles x 128 units
    const int bt = blockIdx.x >> 5;    // 32 batch tiles x 32 batches
    const int b0 = bt * 32;
    const int u0 = ut * 128;
    const int p0 = ut * 64;

    const int q  = tid & 7;            // k-quad: local k = 4q..4q+3
    const int rq = tid >> 3;           // row subgroup 0..31

    const float* xc = X + (size_t)(b0 + 8 * wid) * IND;  // wave-uniform -> s_load

    float acc[8][2];
#pragma unroll
    for (int i = 0; i < 8; ++i) { acc[i][0] = 0.f; acc[i][1] = 0.f; }

    float4 pf[4];
#define STAGE_LOAD(c) do {                                                     \
    _Pragma("unroll")                                                          \
    for (int j = 0; j < 4; ++j)                                                \
        pf[j] = *reinterpret_cast<const float4*>(                              \
            W + (size_t)(u0 + rq + 32 * j) * IND + (c) * KC + q * 4);          \
    } while (0)

#define STAGE_WRITE(buf) do {                                                  \
    const int kp0 = 2 * q, kp1 = 2 * q + 1;                                    \
    const int sw0 = (kp0 & 7) << 2, sw1 = (kp1 & 7) << 2;                      \
    _Pragma("unroll")                                                          \
    for (int j = 0; j < 4; ++j) {                                              \
        const int u2 = 2 * (rq + 32 * j);                                      \
        *reinterpret_cast<float2*>(&Ws[buf][kp0][u2 ^ sw0]) =                  \
            make_float2(pf[j].x, pf[j].y);                                     \
        *reinterpret_cast<float2*>(&Ws[buf][kp1][u2 ^ sw1]) =                  \
            make_float2(pf[j].z, pf[j].w);                                     \
    }                                                                          \
    } while (0)

    // LDS-only barrier: global loads/stores stay in flight across it.
#define LDS_BARRIER() do {                                                     \
    asm volatile("s_waitcnt lgkmcnt(0)" ::: "memory");                         \
    __builtin_amdgcn_s_barrier();                                              \
    } while (0)

    STAGE_LOAD(0);
    STAGE_WRITE(0);
    LDS_BARRIER();

    for (int c = 0; c < IND / KC; ++c) {
        const int cur = c & 1;
        if (c < IND / KC - 1) STAGE_LOAD(c + 1);   // prefetch (no wait yet)

        // zero-slot stores: one rc per chunk, after the prefetch loads;
        // never drained by the LDS-only barriers.
        {
            const int zrc = (int)((0xEDB87421u >> (4 * c)) & 0xFu);
            float* zp = outf + (size_t)(b0 + 8 * wid) * 32768
                       + (size_t)zrc * 2048 + p0 + lane;
#pragma unroll
            for (int i = 0; i < 8; ++i)
                zp[(size_t)i * 32768] = 0.f;
        }

        // ---- W-read phase: ALL 16 ds_read_b128 of the chunk up front.
        // After the single implicit lgkm wait, the FMA body has NO DS ops in
        // flight, so its lgkmcnt(0) waits cover only pipelined X s_loads
        // (the SMEM/DS shared-counter drain was the per-kp stall).
        float4 wr[16];
#pragma unroll
        for (int kp = 0; kp < 16; ++kp)
            wr[kp] = *reinterpret_cast<const float4*>(
                &Ws[cur][kp][(4 * lane) ^ ((kp & 7) << 2)]);

        // ---- FMA phase: pure FMA + scalar X loads ----
#pragma unroll
        for (int kp = 0; kp < 16; ++kp) {
            const int kg = c * KC + 2 * kp;
            // wr[kp] = {W[2l][2kp], W[2l][2kp+1], W[2l+1][2kp], W[2l+1][2kp+1]}
#pragma unroll
            for (int i = 0; i < 8; ++i) {
                const float x0 = xc[i * IND + kg];      // wave-uniform s_load
                const float x1 = xc[i * IND + kg + 1];
                acc[i][0] = fmaf(x0, wr[kp].x, acc[i][0]);
                acc[i][0] = fmaf(x1, wr[kp].y, acc[i][0]);
                acc[i][1] = fmaf(x0, wr[kp].z, acc[i][1]);
                acc[i][1] = fmaf(x1, wr[kp].w, acc[i][1]);
            }
        }
        if (c < IND / KC - 1) {
            STAGE_WRITE(cur ^ 1);                  // vmcnt wait: only its loads
            LDS_BARRIER();
        }
    }
#undef STAGE_LOAD
#undef STAGE_WRITE
#undef LDS_BARRIER

    // ---- epilogue: lane owns pair p0+lane (units u0+2lane, +1), 8 batches ----
    const float2 bv = *reinterpret_cast<const float2*>(bias + u0 + 2 * lane);

#pragma unroll
    for (int i = 0; i < 8; ++i) {
        const int b = b0 + 8 * wid + i;
        const float tA = acc[i][0] + bv.x;
        const float tB = acc[i][1] + bv.y;
        float sA, cA, sB, cB;
        __sincosf(tA, &sA, &cA);
        __sincosf(tB, &sB, &cB);
        const float ca = 0.5f * (1.f + cA);   // cos^2(tA/2)
        const float sa = 0.5f * (1.f - cA);   // sin^2(tA/2)
        const float cb = 0.5f * (1.f + cB);
        const float sb = 0.5f * (1.f - cB);
        const float oo = 0.25f * sA * sB;     // sin(tA)/2 * sin(tB)/2

        float* bp = outf + (size_t)b * 32768 + p0 + lane;
        bp[ 0 * 2048] =  ca * cb;
        bp[ 3 * 2048] = -oo;
        bp[ 5 * 2048] =  ca * sb;
        bp[ 6 * 2048] =  oo;
        bp[ 9 * 2048] =  oo;
        bp[10 * 2048] =  sa * cb;
        bp[12 * 2048] = -oo;
        bp[15 * 2048] =  sa * sb;
    }
}

extern "C" void kernel_launch(void* const* d_in, const int* in_sizes, int n_in,
                              void* d_out, int out_size, void* d_ws, size_t ws_size,
                              hipStream_t stream) {
    const float* X  = (const float*)d_in[0];
    const float* W  = (const float*)d_in[1];
    const float* bv = (const float*)d_in[2];

    // R20's proven shape: 32 bt x 32 ut = 1024 blocks, 256 threads, 4 blocks/CU.
    FeatureEncodingLayer_30374008718005_kernel<<<dim3(1024), dim3(256), 0, stream>>>(
        X, W, bv, (float*)d_out);
}